// Round 10
// baseline (186.522 us; speedup 1.0000x reference)
//
#include <hip/hip_runtime.h>
#include <hip/hip_bf16.h>

#define T_SEQ 2048
#define NHEAD 16
#define HDIM  64
#define CDIM  1024

typedef __attribute__((ext_vector_type(8))) short bf16x8;
typedef __attribute__((ext_vector_type(4))) short bf16x4;
typedef __attribute__((ext_vector_type(4))) float f32x4;

__device__ __forceinline__ unsigned short f2bf(float f) {
  union { __hip_bfloat16 h; unsigned short u; } c;
  c.h = __float2bfloat16(f);
  return c.u;
}

#define GLD16(g, l) __builtin_amdgcn_global_load_lds( \
  (const __attribute__((address_space(1))) void*)(g), \
  (__attribute__((address_space(3))) void*)(l), 16, 0, 0)

// ---------------- elementwise f32 -> bf16 cast (vectorized) ----------------
__global__ void cvt_bf16(const float* __restrict__ in, unsigned short* __restrict__ out, int n4) {
  const int i = blockIdx.x * 256 + threadIdx.x;
  if (i >= n4) return;
  const float4 v = ((const float4*)in)[i];
  ushort4 o;
  o.x = f2bf(v.x); o.y = f2bf(v.y); o.z = f2bf(v.z); o.w = f2bf(v.w);
  ((ushort4*)out)[i] = o;
}

// ---------------- tiled transpose f32[R][C] -> bf16[C][R] ----------------
__global__ void transpose_cvt(const float* __restrict__ in, unsigned short* __restrict__ out,
                              int R, int C) {
  __shared__ float tile[32][33];
  const int tx = threadIdx.x & 31, ty = threadIdx.x >> 5;
  const int c0 = blockIdx.x * 32, r0 = blockIdx.y * 32;
#pragma unroll
  for (int i = 0; i < 32; i += 8)
    tile[ty + i][tx] = in[(size_t)(r0 + ty + i) * C + c0 + tx];
  __syncthreads();
#pragma unroll
  for (int i = 0; i < 32; i += 8)
    out[(size_t)(c0 + ty + i) * R + r0 + tx] = f2bf(tile[tx][ty + i]);
}

// ---------------- bf16 MFMA GEMM: C[M][N] = A[M][K] * BT[N][K]^T + bias ----------------
template<int OUTF32>
__global__ __launch_bounds__(256, 3)
void gemm_bt(const unsigned short* __restrict__ A, const unsigned short* __restrict__ BT,
             const float* __restrict__ bias, void* __restrict__ outp,
             int M, int N, int K) {
  const int tid = threadIdx.x;
  const int w = tid >> 6, lane = tid & 63;
  const int lg = lane >> 4, l15 = lane & 15;
  const int wr = w >> 1, wc = w & 1;

  const int nb = gridDim.x * gridDim.y;
  const int fid = blockIdx.y * gridDim.x + blockIdx.x;
  const int swz = (fid & 7) * (nb >> 3) + (fid >> 3);
  const int n0 = (swz % gridDim.x) * 128, m0 = (swz / gridDim.x) * 128;

  __shared__ unsigned short As[128 * 32];
  __shared__ unsigned short Bs[128 * 32];

  f32x4 acc[4][4] = {};

  for (int k0 = 0; k0 < K; k0 += 32) {
    __syncthreads();
#pragma unroll
    for (int i = 0; i < 2; ++i) {
      const int cb = i * 256 + w * 64;
      const int c  = cb + lane;
      const int row = c >> 2, slot = c & 3;
      GLD16(A  + (size_t)(m0 + row) * K + k0 + slot * 8, (char*)As + cb * 16);
      GLD16(BT + (size_t)(n0 + row) * K + k0 + slot * 8, (char*)Bs + cb * 16);
    }
    __syncthreads();
    bf16x8 af[4], bfr[4];
#pragma unroll
    for (int mt = 0; mt < 4; ++mt)
      af[mt] = *(const bf16x8*)&As[(wr * 64 + mt * 16 + l15) * 32 + lg * 8];
#pragma unroll
    for (int nt = 0; nt < 4; ++nt)
      bfr[nt] = *(const bf16x8*)&Bs[(wc * 64 + nt * 16 + l15) * 32 + lg * 8];
#pragma unroll
    for (int mt = 0; mt < 4; ++mt)
#pragma unroll
      for (int nt = 0; nt < 4; ++nt)
        acc[mt][nt] = __builtin_amdgcn_mfma_f32_16x16x32_bf16(af[mt], bfr[nt], acc[mt][nt], 0, 0, 0);
  }

#pragma unroll
  for (int mt = 0; mt < 4; ++mt) {
#pragma unroll
    for (int nt = 0; nt < 4; ++nt) {
      const int col = n0 + wc * 64 + nt * 16 + l15;
      const float bv = bias[col];
#pragma unroll
      for (int j = 0; j < 4; ++j) {
        const int row = m0 + wr * 64 + mt * 16 + lg * 4 + j;
        const float v = acc[mt][nt][j] + bv;
        if (OUTF32) ((float*)outp)[(size_t)row * N + col] = v;
        else ((unsigned short*)outp)[(size_t)row * N + col] = f2bf(v);
      }
    }
  }
}

// ---------------- causal flash attention v10 ----------------
// v9 cadence (KVBLK=128, 17 uniform iters, in-block {p,15-p} pairing, grid 512)
// with QBLK=32 per wave: 4 waves x 32 q-rows = 128-row q-tile, 256 threads.
// K/V ds_reads shared across each wave's 2 q-fragments -> LDS read traffic halved.
// All v9-verified layouts: K row-permute + slot swizzle, V chunk swizzle, reg-only P.
#define EXPC 0.18033688f   /* 0.125 * log2(e) */
__global__ __launch_bounds__(256, 2)
void attn_causal10(const unsigned short* __restrict__ qkv, unsigned short* __restrict__ att) {
  const int tid = threadIdx.x;
  const int w = tid >> 6, lane = tid & 63;
  const int lg = lane >> 4, l15 = lane & 15;

  const int fid = blockIdx.x;                   // 0..511
  const int f2 = (fid & 7) * 64 + (fid >> 3);   // XCD-chunked remap (bijective)
  const int pair = f2 & 7, bh = f2 >> 3;
  const int b = bh >> 4, h = bh & 15;

  __shared__ unsigned short Kl[2][2][128][32];  // [buf][kc][ldsrow][el] 32 KB
  __shared__ unsigned short Vt[2][64][128];     // [buf][d][kv] chunk-swizzled 32 KB

  const unsigned short* base = qkv + (size_t)b * T_SEQ * 3072;

  // K stage: 1024 chunks of 16B; LDS row slot holds bit-permuted global kv.
  auto STAGE_K = [&](int kv0, int buf) {
#pragma unroll
    for (int i = 0; i < 4; ++i) {
      const int c = i * 256 + tid;
      const int kc = c >> 9, slot = (c >> 2) & 127;
      const int s2 = (c & 3) ^ ((slot >> 1) & 3);
      const int v = (slot & 99) | ((slot & 8) << 1) | ((slot & 4) << 1) | ((slot & 16) >> 2);
      GLD16(base + (size_t)(kv0 + v) * 3072 + 1024 + h * 64 + kc * 32 + s2 * 8,
            (char*)&Kl[buf][0][0][0] + i * 4096 + w * 1024);
    }
  };

  // V stage: 4 units/thread; unit uu: kv rows {2*p2, 2*p2+1} (p2 = vkp0+16*uu),
  // d cols [vd4*4, +4). Chunk swizzle: phys = (ch&8) | ((ch ^ (r>>3) ^ (r&7)) & 7).
  bf16x4 vra[4], vrb[4];
  const int vkp0 = tid >> 4, vd4 = tid & 15;
  auto VLOAD = [&](int kv0) {
#pragma unroll
    for (int uu = 0; uu < 4; ++uu) {
      const unsigned short* p = base + (size_t)(kv0 + 2 * (vkp0 + 16 * uu)) * 3072 + 2048 + h * 64 + vd4 * 4;
      vra[uu] = *(const bf16x4*)p;
      vrb[uu] = *(const bf16x4*)(p + 3072);
    }
  };
  auto VWRITE = [&](int buf) {
#pragma unroll
    for (int uu = 0; uu < 4; ++uu) {
      const int p2 = vkp0 + 16 * uu;
      const int ch = p2 >> 2, cl = (p2 & 3) * 2;
#pragma unroll
      for (int j = 0; j < 4; ++j) {
        const int r = vd4 * 4 + j;
        const int phys = (ch & 8) | ((ch ^ (r >> 3) ^ (r & 7)) & 7);
        const unsigned int pk = (unsigned short)vra[uu][j] |
                                ((unsigned int)(unsigned short)vrb[uu][j] << 16);
        *(unsigned int*)&Vt[buf][r][phys * 8 + cl] = pk;
      }
    }
  };

  bf16x8 ones;
#pragma unroll
  for (int j = 0; j < 8; ++j) ones[j] = (short)0x3F80;   // bf16 1.0

  for (int half = 0; half < 2; ++half) {
    const int qt = half ? (15 - pair) : pair;
    const int q0 = qt << 7;
    const int ntl = qt + 1;                     // KV128 tiles
    const int qminS = __builtin_amdgcn_readfirstlane(q0 + w * 32);  // wave-uniform

    bf16x8 qf[2][2];
#pragma unroll
    for (int qr = 0; qr < 2; ++qr)
#pragma unroll
      for (int kc = 0; kc < 2; ++kc)
        qf[qr][kc] = *(const bf16x8*)(base + (size_t)(qminS + qr * 16 + l15) * 3072 +
                                      h * 64 + kc * 32 + lg * 8);

    f32x4 oacc[2][4] = {};
    f32x4 lsum[2] = {};
    float m[2] = {-1e30f, -1e30f};

    STAGE_K(0, 0);
    VLOAD(0);
    VWRITE(0);
    __syncthreads();

    for (int t = 0; t < ntl; ++t) {
      const int cur = t & 1, nxt = cur ^ 1;
      const bool pf = (t + 1) < ntl;
      if (pf) { STAGE_K((t + 1) << 7, nxt); VLOAD((t + 1) << 7); }
      const int kv0 = t << 7;

      // ---- QK^T swapped: 32 MFMA over 128 kv x 32 q, K reads shared ----
      const int ksl = (lg ^ ((l15 >> 1) & 3)) * 8;
      f32x4 sc[2][8];
      __builtin_amdgcn_s_setprio(1);
#pragma unroll
      for (int kg = 0; kg < 8; ++kg) {
        f32x4 s0 = {}, s1 = {};
#pragma unroll
        for (int kc = 0; kc < 2; ++kc) {
          bf16x8 kf = *(const bf16x8*)&Kl[cur][kc][kg * 16 + l15][ksl];
          s0 = __builtin_amdgcn_mfma_f32_16x16x32_bf16(kf, qf[0][kc], s0, 0, 0, 0);
          s1 = __builtin_amdgcn_mfma_f32_16x16x32_bf16(kf, qf[1][kc], s1, 0, 0, 0);
        }
        sc[0][kg] = s0; sc[1][kg] = s1;
      }
      __builtin_amdgcn_s_setprio(0);

      // ---- mask: only the diagonal tile (t == qt) ----
      if (t == qt) {
#pragma unroll
        for (int qr = 0; qr < 2; ++qr) {
          const int qme = qminS + qr * 16 + l15;
#pragma unroll
          for (int kg = 0; kg < 8; ++kg) {
            const int colb = kv0 + ((kg >> 1) << 5) + ((kg & 1) << 2) + lg * 8;
#pragma unroll
            for (int j = 0; j < 4; ++j)
              if (colb + j > qme) sc[qr][kg][j] = -1e30f;
          }
        }
      }

      // ---- tree max per fragment ----
      float mx[2];
#pragma unroll
      for (int qr = 0; qr < 2; ++qr) {
        float m1 = -1e30f;
#pragma unroll
        for (int kg = 0; kg < 8; ++kg) {
          const float a = fmaxf(sc[qr][kg][0], sc[qr][kg][1]);
          const float c2 = fmaxf(sc[qr][kg][2], sc[qr][kg][3]);
          m1 = fmaxf(m1, fmaxf(a, c2));
        }
        mx[qr] = m1;
      }

      // ---- defer-max rescale (rare) ----
      if (__any(fmaxf(mx[0] - m[0], mx[1] - m[1]) > 55.4f)) {
#pragma unroll
        for (int qr = 0; qr < 2; ++qr) {
          float mw = fmaxf(mx[qr], __shfl_xor(mx[qr], 16));
          mw = fmaxf(mw, __shfl_xor(mw, 32));
          const float mnew = fmaxf(m[qr], mw);
          const float alc = exp2f((m[qr] - mnew) * EXPC);
          m[qr] = mnew;
          float alq[4];
#pragma unroll
          for (int j = 0; j < 4; ++j)
            alq[j] = __shfl(alc, (lane & 48) | (lg * 4 + j));
#pragma unroll
          for (int j = 0; j < 4; ++j) {
            lsum[qr][j] *= alq[j];
#pragma unroll
            for (int dt = 0; dt < 4; ++dt) oacc[qr][dt][j] *= alq[j];
          }
        }
      }

      // ---- exp -> PV A-fragments (registers, same lane) ----
      bf16x8 pa[2][4];
#pragma unroll
      for (int qr = 0; qr < 2; ++qr) {
        const float mc = m[qr] * EXPC;
#pragma unroll
        for (int kg = 0; kg < 8; ++kg) {
          const int ks = kg >> 1, off = (kg & 1) * 4;
#pragma unroll
          for (int j = 0; j < 4; ++j) {
            const float p = exp2f(__fmaf_rn(sc[qr][kg][j], EXPC, -mc));
            pa[qr][ks][off + j] = (short)f2bf(p);
          }
        }
      }

      // ---- lsum via ones-MFMA + PV (V reads shared across fragments) ----
      __builtin_amdgcn_s_setprio(1);
#pragma unroll
      for (int ks = 0; ks < 4; ++ks) {
        lsum[0] = __builtin_amdgcn_mfma_f32_16x16x32_bf16(pa[0][ks], ones, lsum[0], 0, 0, 0);
        lsum[1] = __builtin_amdgcn_mfma_f32_16x16x32_bf16(pa[1][ks], ones, lsum[1], 0, 0, 0);
      }
#pragma unroll
      for (int dt = 0; dt < 4; ++dt) {
        f32x4 o0 = oacc[0][dt], o1 = oacc[1][dt];
        const int d = dt * 16 + l15;
        const int gx = (d >> 3) ^ (d & 7);      // V chunk swizzle (low 3 bits)
#pragma unroll
        for (int ks = 0; ks < 4; ++ks) {
          const int slot = ks * 4 + lg;
          const int phys = (slot & 8) | ((slot ^ gx) & 7);
          bf16x8 vb = *(const bf16x8*)&Vt[cur][d][phys * 8];
          o0 = __builtin_amdgcn_mfma_f32_16x16x32_bf16(pa[0][ks], vb, o0, 0, 0, 0);
          o1 = __builtin_amdgcn_mfma_f32_16x16x32_bf16(pa[1][ks], vb, o1, 0, 0, 0);
        }
        oacc[0][dt] = o0; oacc[1][dt] = o1;
      }
      __builtin_amdgcn_s_setprio(0);

      if (pf) VWRITE(nxt);
      __syncthreads();   // drains vmcnt (K gld_lds) + lgkm (V writes); swap buffers
    }

    // ---- epilogue: normalize via rcp, store ----
#pragma unroll
    for (int qr = 0; qr < 2; ++qr) {
      f32x4 inv;
#pragma unroll
      for (int j = 0; j < 4; ++j) inv[j] = __builtin_amdgcn_rcpf(lsum[qr][j]);
#pragma unroll
      for (int dt = 0; dt < 4; ++dt)
#pragma unroll
        for (int j = 0; j < 4; ++j) {
          const int q = qminS + qr * 16 + lg * 4 + j;
          att[(size_t)(b * T_SEQ + q) * CDIM + h * HDIM + dt * 16 + l15] =
              f2bf(oacc[qr][dt][j] * inv[j]);
        }
    }
  }
}

// ---------------- launcher ----------------
extern "C" void kernel_launch(void* const* d_in, const int* in_sizes, int n_in,
                              void* d_out, int out_size, void* d_ws, size_t ws_size,
                              hipStream_t stream) {
  const float* x      = (const float*)d_in[0];
  const float* w_attn = (const float*)d_in[1];
  const float* b_attn = (const float*)d_in[2];
  const float* w_proj = (const float*)d_in[3];
  const float* b_proj = (const float*)d_in[4];

  char* ws = (char*)d_ws;
  unsigned short* xb  = (unsigned short*)(ws + 0);           // 8192*1024 bf16
  unsigned short* wat = (unsigned short*)(ws + 16777216);    // 3072*1024 bf16 (w_attn^T)
  unsigned short* wpt = (unsigned short*)(ws + 23068672);    // 1024*1024 bf16 (w_proj^T)
  unsigned short* qkv = (unsigned short*)(ws + 25165824);    // 8192*3072 bf16
  unsigned short* att = (unsigned short*)(ws + 75497472);    // 8192*1024 bf16

  cvt_bf16<<<8192, 256, 0, stream>>>(x, xb, 2097152);
  transpose_cvt<<<dim3(96, 32), 256, 0, stream>>>(w_attn, wat, 1024, 3072);
  transpose_cvt<<<dim3(32, 32), 256, 0, stream>>>(w_proj, wpt, 1024, 1024);
  gemm_bt<0><<<dim3(24, 64), 256, 0, stream>>>(xb, wat, b_attn, (void*)qkv, 8192, 3072, 1024);
  attn_causal10<<<dim3(512), 256, 0, stream>>>(qkv, att);
  gemm_bt<1><<<dim3(8, 64), 256, 0, stream>>>(att, wpt, b_proj, d_out, 8192, 1024, 1024);
}

// Round 11
// 172.406 us; speedup vs baseline: 1.0819x; 1.0819x over previous
//
#include <hip/hip_runtime.h>
#include <hip/hip_bf16.h>

#define T_SEQ 2048
#define NHEAD 16
#define HDIM  64
#define CDIM  1024

typedef __attribute__((ext_vector_type(8))) short bf16x8;
typedef __attribute__((ext_vector_type(4))) short bf16x4;
typedef __attribute__((ext_vector_type(4))) float f32x4;

__device__ __forceinline__ unsigned short f2bf(float f) {
  union { __hip_bfloat16 h; unsigned short u; } c;
  c.h = __float2bfloat16(f);
  return c.u;
}

#define GLD16(g, l) __builtin_amdgcn_global_load_lds( \
  (const __attribute__((address_space(1))) void*)(g), \
  (__attribute__((address_space(3))) void*)(l), 16, 0, 0)

// ---------------- merged prep: x->bf16 cast + both weight transposes ----------------
// blocks [0,8192): cvt x (float4 each);  [8192,11264): w_attn^T;  [11264,12288): w_proj^T
__global__ void prep_all(const float* __restrict__ x, const float* __restrict__ wa,
                         const float* __restrict__ wp, unsigned short* __restrict__ xb,
                         unsigned short* __restrict__ wat, unsigned short* __restrict__ wpt) {
  __shared__ float tile[32][33];
  const int bid = blockIdx.x;
  if (bid < 8192) {
    const int i = bid * 256 + threadIdx.x;
    const float4 v = ((const float4*)x)[i];
    ushort4 o;
    o.x = f2bf(v.x); o.y = f2bf(v.y); o.z = f2bf(v.z); o.w = f2bf(v.w);
    ((ushort4*)xb)[i] = o;
    return;
  }
  const float* in; unsigned short* out; int R, C, bx, by;
  if (bid < 11264) { in = wa; out = wat; R = 1024; C = 3072; bx = (bid - 8192) % 96; by = (bid - 8192) / 96; }
  else             { in = wp; out = wpt; R = 1024; C = 1024; bx = (bid - 11264) % 32; by = (bid - 11264) / 32; }
  const int tx = threadIdx.x & 31, ty = threadIdx.x >> 5;
  const int c0 = bx * 32, r0 = by * 32;
#pragma unroll
  for (int i = 0; i < 32; i += 8)
    tile[ty + i][tx] = in[(size_t)(r0 + ty + i) * C + c0 + tx];
  __syncthreads();
#pragma unroll
  for (int i = 0; i < 32; i += 8)
    out[(size_t)(c0 + ty + i) * R + r0 + tx] = f2bf(tile[tx][ty + i]);
}

// ---------------- bf16 MFMA GEMM: C[M][N] = A[M][K] * BT[N][K]^T + bias ----------------
// 128x128 tile, BK=64 (half the barrier-drain events of BK=32), 4 waves (2x2).
// LDS slot-XOR swizzle: stage fetches global slot s^(row&7) into phys slot s;
// frag reads use phys = (ks*4+lg)^(l15&7) -> 2-way banks (free). XCD-chunked swizzle.
template<int OUTF32>
__global__ __launch_bounds__(256, 2)
void gemm_bt(const unsigned short* __restrict__ A, const unsigned short* __restrict__ BT,
             const float* __restrict__ bias, void* __restrict__ outp,
             int M, int N, int K) {
  const int tid = threadIdx.x;
  const int w = tid >> 6, lane = tid & 63;
  const int lg = lane >> 4, l15 = lane & 15;
  const int wr = w >> 1, wc = w & 1;

  const int nb = gridDim.x * gridDim.y;
  const int fid = blockIdx.y * gridDim.x + blockIdx.x;
  const int swz = (fid & 7) * (nb >> 3) + (fid >> 3);
  const int n0 = (swz % gridDim.x) * 128, m0 = (swz / gridDim.x) * 128;

  __shared__ unsigned short As[128 * 64];
  __shared__ unsigned short Bs[128 * 64];

  f32x4 acc[4][4] = {};

  for (int k0 = 0; k0 < K; k0 += 64) {
    __syncthreads();
#pragma unroll
    for (int i = 0; i < 4; ++i) {
      const int cb = i * 256 + w * 64;   // wave-uniform chunk base
      const int c  = cb + lane;
      const int row = c >> 3, s = c & 7;
      const int sg = s ^ (row & 7);      // pre-swizzled source slot
      GLD16(A  + (size_t)(m0 + row) * K + k0 + sg * 8, (char*)As + cb * 16);
      GLD16(BT + (size_t)(n0 + row) * K + k0 + sg * 8, (char*)Bs + cb * 16);
    }
    __syncthreads();
#pragma unroll
    for (int ks = 0; ks < 2; ++ks) {
      bf16x8 af[4], bfr[4];
#pragma unroll
      for (int mt = 0; mt < 4; ++mt) {
        const int row = wr * 64 + mt * 16 + l15;
        af[mt] = *(const bf16x8*)&As[row * 64 + (((ks * 4 + lg) ^ (l15 & 7)) << 3)];
      }
#pragma unroll
      for (int nt = 0; nt < 4; ++nt) {
        const int row = wc * 64 + nt * 16 + l15;
        bfr[nt] = *(const bf16x8*)&Bs[row * 64 + (((ks * 4 + lg) ^ (l15 & 7)) << 3)];
      }
#pragma unroll
      for (int mt = 0; mt < 4; ++mt)
#pragma unroll
        for (int nt = 0; nt < 4; ++nt)
          acc[mt][nt] = __builtin_amdgcn_mfma_f32_16x16x32_bf16(af[mt], bfr[nt], acc[mt][nt], 0, 0, 0);
    }
  }

#pragma unroll
  for (int mt = 0; mt < 4; ++mt) {
#pragma unroll
    for (int nt = 0; nt < 4; ++nt) {
      const int col = n0 + wc * 64 + nt * 16 + l15;
      const float bv = bias[col];
#pragma unroll
      for (int j = 0; j < 4; ++j) {
        const int row = m0 + wr * 64 + mt * 16 + lg * 4 + j;
        const float v = acc[mt][nt][j] + bv;
        if (OUTF32) ((float*)outp)[(size_t)row * N + col] = v;
        else ((unsigned short*)outp)[(size_t)row * N + col] = f2bf(v);
      }
    }
  }
}

// ---------------- causal flash attention (v5 exact, proven 89 us; + rcp epilogue) ----------------
// 512 threads = 8 waves x 16 q-rows; in-block pairing {p,15-p}: uniform 34 KV64 iters.
// K rows bit-permuted in LDS so swapped-QK^T output == PV A-fragment (reg-only P);
// lsum via ones-MFMA in O layout; scalarized mask; K slot swizzle; V chunk swizzle.
#define EXPC 0.18033688f   /* 0.125 * log2(e) */
__global__ __launch_bounds__(512, 4)
void attn_causal5(const unsigned short* __restrict__ qkv, unsigned short* __restrict__ att) {
  const int tid = threadIdx.x;
  const int w = tid >> 6, lane = tid & 63;
  const int lg = lane >> 4, l15 = lane & 15;

  const int fid = blockIdx.x;                   // 0..511
  const int f2 = (fid & 7) * 64 + (fid >> 3);   // XCD-chunked remap (bijective)
  const int pair = f2 & 7, bh = f2 >> 3;
  const int b = bh >> 4, h = bh & 15;

  __shared__ unsigned short Kl[2][2][64][32];   // [buf][kc][ldsrow][el], slot+row permuted
  __shared__ unsigned short Vt[2][64][64];      // [buf][d][kv], chunk-swizzled

  const unsigned short* base = qkv + (size_t)b * T_SEQ * 3072;

  auto STAGE_K = [&](int kv0, int buf) {
    const int c = tid;                          // 512 chunks of 16B
    const int kc = c >> 8, slot = (c >> 2) & 63;
    const int s2 = (c & 3) ^ ((slot >> 1) & 3);
    const int v = (slot & 35) | ((slot & 8) << 1) | ((slot & 4) << 1) | ((slot & 16) >> 2);
    GLD16(base + (size_t)(kv0 + v) * 3072 + 1024 + h * 64 + kc * 32 + s2 * 8,
          (char*)&Kl[buf][0][0][0] + w * 1024);
  };

  bf16x4 vra, vrb;
  const int vkp = tid >> 4, vd4 = tid & 15;
  auto VLOAD = [&](int kv0) {
    const unsigned short* p = base + (size_t)(kv0 + 2 * vkp) * 3072 + 2048 + h * 64 + vd4 * 4;
    vra = *(const bf16x4*)p;
    vrb = *(const bf16x4*)(p + 3072);
  };
  auto VWRITE = [&](int buf) {
    const int ch = vkp >> 2, cl = (vkp & 3) * 2;
#pragma unroll
    for (int j = 0; j < 4; ++j) {
      const int r = vd4 * 4 + j;
      const unsigned int u = (unsigned short)vra[j] |
                             ((unsigned int)(unsigned short)vrb[j] << 16);
      *(unsigned int*)&Vt[buf][r][((ch ^ (r >> 3) ^ (r & 7)) << 3) + cl] = u;
    }
  };

  bf16x8 ones;
#pragma unroll
  for (int j = 0; j < 8; ++j) ones[j] = (short)0x3F80;   // bf16 1.0

  for (int half = 0; half < 2; ++half) {
    const int qt = half ? (15 - pair) : pair;
    const int q0 = qt << 7;
    const int ntl = (qt + 1) << 1;              // KV64 tiles
    const int qminS = __builtin_amdgcn_readfirstlane(q0 + w * 16);
    const int qme = qminS + l15;

    bf16x8 qf[2];
#pragma unroll
    for (int kc = 0; kc < 2; ++kc)
      qf[kc] = *(const bf16x8*)(base + (size_t)qme * 3072 + h * 64 + kc * 32 + lg * 8);

    f32x4 oacc[4] = {};
    f32x4 lsum = {};
    float m = -1e30f;

    STAGE_K(0, 0);
    VLOAD(0);
    VWRITE(0);
    __syncthreads();

    for (int t = 0; t < ntl; ++t) {
      const int cur = t & 1, nxt = cur ^ 1;
      const bool pf = (t + 1) < ntl;
      if (pf) { STAGE_K((t + 1) << 6, nxt); VLOAD((t + 1) << 6); }
      const int kv0 = t << 6;

      if (kv0 <= qminS + 15) {                  // wave has unmasked work
        const int ksl = (lg ^ ((l15 >> 1) & 3)) * 8;
        f32x4 sc[4];
        __builtin_amdgcn_s_setprio(1);
#pragma unroll
        for (int kg = 0; kg < 4; ++kg) {
          f32x4 s = {};
#pragma unroll
          for (int kc = 0; kc < 2; ++kc) {
            bf16x8 kf = *(const bf16x8*)&Kl[cur][kc][kg * 16 + l15][ksl];
            s = __builtin_amdgcn_mfma_f32_16x16x32_bf16(kf, qf[kc], s, 0, 0, 0);
          }
          sc[kg] = s;
        }
        __builtin_amdgcn_s_setprio(0);

        // ---- mask (diagonal tiles only, scalar-guarded) ----
        float sv[4][4];
        if (kv0 + 63 > qminS) {
#pragma unroll
          for (int kg = 0; kg < 4; ++kg) {
            const int colb = kv0 + ((kg >> 1) << 5) + ((kg & 1) << 2) + lg * 8;
#pragma unroll
            for (int j = 0; j < 4; ++j)
              sv[kg][j] = (colb + j <= qme) ? sc[kg][j] : -1e30f;
          }
        } else {
#pragma unroll
          for (int kg = 0; kg < 4; ++kg)
#pragma unroll
            for (int j = 0; j < 4; ++j) sv[kg][j] = sc[kg][j];
        }

        // ---- tree max ----
        float mx = -1e30f;
#pragma unroll
        for (int kg = 0; kg < 4; ++kg) {
          const float a = fmaxf(sv[kg][0], sv[kg][1]);
          const float c2 = fmaxf(sv[kg][2], sv[kg][3]);
          mx = fmaxf(mx, fmaxf(a, c2));
        }

        // ---- defer-max rescale (rare) ----
        if (__any(mx > m + 55.4f)) {
          float mw = fmaxf(mx, __shfl_xor(mx, 16));
          mw = fmaxf(mw, __shfl_xor(mw, 32));
          const float mnew = fmaxf(m, mw);
          const float alc = exp2f((m - mnew) * EXPC);
          m = mnew;
          float alq[4];
#pragma unroll
          for (int j = 0; j < 4; ++j)
            alq[j] = __shfl(alc, (lane & 48) | (lg * 4 + j));
#pragma unroll
          for (int j = 0; j < 4; ++j) {
            lsum[j] *= alq[j];
#pragma unroll
            for (int dt = 0; dt < 4; ++dt) oacc[dt][j] *= alq[j];
          }
        }

        // ---- exp -> PV A-fragments (registers, same lane) ----
        const float mc = m * EXPC;
        bf16x8 pa[2];
#pragma unroll
        for (int kg = 0; kg < 4; ++kg) {
          const int ks = kg >> 1, off = (kg & 1) * 4;
#pragma unroll
          for (int j = 0; j < 4; ++j) {
            const float p = exp2f(__fmaf_rn(sv[kg][j], EXPC, -mc));
            pa[ks][off + j] = (short)f2bf(p);
          }
        }

        // ---- lsum via ones-MFMA + PV ----
        __builtin_amdgcn_s_setprio(1);
        lsum = __builtin_amdgcn_mfma_f32_16x16x32_bf16(pa[0], ones, lsum, 0, 0, 0);
        lsum = __builtin_amdgcn_mfma_f32_16x16x32_bf16(pa[1], ones, lsum, 0, 0, 0);
#pragma unroll
        for (int dt = 0; dt < 4; ++dt) {
          f32x4 o = oacc[dt];
          const int d = dt * 16 + l15;
          const int gx = (d >> 3) ^ (d & 7);    // V chunk swizzle
#pragma unroll
          for (int ks = 0; ks < 2; ++ks) {
            bf16x8 vb = *(const bf16x8*)&Vt[cur][d][((ks * 4 + lg) ^ gx) << 3];
            o = __builtin_amdgcn_mfma_f32_16x16x32_bf16(pa[ks], vb, o, 0, 0, 0);
          }
          oacc[dt] = o;
        }
        __builtin_amdgcn_s_setprio(0);
      }

      if (pf) VWRITE(nxt);
      __syncthreads();   // drains vmcnt (K gld_lds) + lgkm (V writes); swap buffers
    }

    // ---- epilogue: normalize via rcp, store ----
    f32x4 inv;
#pragma unroll
    for (int j = 0; j < 4; ++j) inv[j] = __builtin_amdgcn_rcpf(lsum[j]);
#pragma unroll
    for (int dt = 0; dt < 4; ++dt)
#pragma unroll
      for (int j = 0; j < 4; ++j) {
        const int q = qminS + lg * 4 + j;
        att[(size_t)(b * T_SEQ + q) * CDIM + h * HDIM + dt * 16 + l15] =
            f2bf(oacc[dt][j] * inv[j]);
      }
  }
}

// ---------------- launcher ----------------
extern "C" void kernel_launch(void* const* d_in, const int* in_sizes, int n_in,
                              void* d_out, int out_size, void* d_ws, size_t ws_size,
                              hipStream_t stream) {
  const float* x      = (const float*)d_in[0];
  const float* w_attn = (const float*)d_in[1];
  const float* b_attn = (const float*)d_in[2];
  const float* w_proj = (const float*)d_in[3];
  const float* b_proj = (const float*)d_in[4];

  char* ws = (char*)d_ws;
  unsigned short* xb  = (unsigned short*)(ws + 0);           // 8192*1024 bf16
  unsigned short* wat = (unsigned short*)(ws + 16777216);    // 3072*1024 bf16 (w_attn^T)
  unsigned short* wpt = (unsigned short*)(ws + 23068672);    // 1024*1024 bf16 (w_proj^T)
  unsigned short* qkv = (unsigned short*)(ws + 25165824);    // 8192*3072 bf16
  unsigned short* att = (unsigned short*)(ws + 75497472);    // 8192*1024 bf16

  prep_all<<<dim3(12288), 256, 0, stream>>>(x, w_attn, w_proj, xb, wat, wpt);
  gemm_bt<0><<<dim3(24, 64), 256, 0, stream>>>(xb, wat, b_attn, (void*)qkv, 8192, 3072, 1024);
  attn_causal5<<<dim3(512), 512, 0, stream>>>(qkv, att);
  gemm_bt<1><<<dim3(8, 64), 256, 0, stream>>>(att, wpt, b_proj, d_out, 8192, 1024, 1024);
}